// Round 4
// baseline (129.753 us; speedup 1.0000x reference)
//
#include <hip/hip_runtime.h>

// BertWordEmbedder: B=64, T=512, H=768, W=256, D=256
// Linearity: mean_t(h_t) @ W  ==  mean_t(h_t @ W).  So:
//   prep_wt:     proj_w [768][256] f32 -> wt [256][768] bf16        (d_ws)
//   prep_bounds: word segment bounds[b][w] via binary search         (d_ws)
//   gemm_tok:    P[32768x256] = hs[32768x768] @ W   (streaming MFMA, bf16 out)
//   pool:        one wave per (b,w): mean of P rows + bias -> out    (L2-hot)
// Empty words: pool outputs 0*sc + bias = bias (matches reference 0@W+b).
// ws: [0) wt 393216 | [393216) bounds 65792 | [524288) P 16777216

#define NB 64
#define NT 512
#define NH 768
#define NW 256
#define ND 256

typedef __attribute__((ext_vector_type(8))) short short8;
typedef __attribute__((ext_vector_type(4))) float f32x4;
typedef __attribute__((ext_vector_type(4))) float float4v;
typedef __attribute__((ext_vector_type(4))) unsigned int uint4v;
typedef __attribute__((ext_vector_type(4))) unsigned short ushort4v;

__device__ __forceinline__ unsigned short f2bf(float f) {
    union { float f; unsigned u; } v; v.f = f;
    unsigned r = v.u + 0x7fffu + ((v.u >> 16) & 1u);  // RNE
    return (unsigned short)(r >> 16);
}
// pack 2 floats -> 2 bf16 in one dword (round-half-up; |err| <= 1/2 ulp + tie bias)
__device__ __forceinline__ unsigned pk2(float lo, float hi) {
    union { float f; unsigned u; } a, b; a.f = lo; b.f = hi;
    return ((b.u + 0x8000u) & 0xffff0000u) | ((a.u + 0x8000u) >> 16);
}

// proj_w [H][D] fp32 -> wt [D][H] bf16
__global__ void prep_wt(const float* __restrict__ w, unsigned short* __restrict__ wt) {
    __shared__ float tile[32][33];
    int tx = threadIdx.x & 31, ty = threadIdx.x >> 5;
    int k0 = blockIdx.x * 32, n0 = blockIdx.y * 32;
    #pragma unroll
    for (int i = 0; i < 4; ++i)
        tile[ty + 8 * i][tx] = w[(size_t)(k0 + ty + 8 * i) * ND + n0 + tx];
    __syncthreads();
    #pragma unroll
    for (int i = 0; i < 4; ++i)
        wt[(size_t)(n0 + ty + 8 * i) * NH + k0 + tx] = f2bf(tile[tx][ty + 8 * i]);
}

// bounds[b][w] = lower_bound(wid[b,:], w), w in [0, NW]; stride NW+1
__global__ void prep_bounds(const int* __restrict__ wid, int* __restrict__ bounds) {
    __shared__ int s[NT];
    int b = blockIdx.x, tid = threadIdx.x;
    s[tid]       = wid[b * NT + tid];
    s[tid + 256] = wid[b * NT + tid + 256];
    __syncthreads();
    for (int w = tid; w <= NW; w += 256) {
        int lo = 0, hi = NT;
        while (lo < hi) { int m = (lo + hi) >> 1; if (s[m] < w) lo = m + 1; else hi = m; }
        bounds[b * (NW + 1) + w] = lo;
    }
}

// P[32768x256] = hs @ W. Block = 64 token-rows x 256 cols, 8 waves.
// Wave: 4 m-tiles x 2 n-tiles. A read direct from global fp32 (full-line
// coalesced per quarter-wave), cvt->bf16 inline; B direct from wt (L1/L2-hot).
__global__ __launch_bounds__(512, 4)
void gemm_tok(const float* __restrict__ hs, const unsigned short* __restrict__ wt,
              unsigned short* __restrict__ P) {
    const int tid = threadIdx.x, wave = tid >> 6, lane = tid & 63;
    const int cl = lane & 15, kg = lane >> 4;
    const size_t r0 = (size_t)blockIdx.x * 64;
    const int c0 = wave * 32;

    const float* aB = hs + (r0 + cl) * NH + kg * 8;
    const unsigned short* bB = wt + (size_t)(c0 + cl) * NH + kg * 8;

    f32x4 acc[4][2];
    #pragma unroll
    for (int mt = 0; mt < 4; ++mt)
        #pragma unroll
        for (int nt = 0; nt < 2; ++nt)
            #pragma unroll
            for (int r = 0; r < 4; ++r) acc[mt][nt][r] = 0.f;

    #pragma unroll 2
    for (int ks = 0; ks < NH / 32; ++ks) {           // 24 K-steps
        short8 a[4];
        #pragma unroll
        for (int mt = 0; mt < 4; ++mt) {
            const float* p = aB + (size_t)mt * 16 * NH + ks * 32;
            float4v lo = *(const float4v*)(p);
            float4v hi = *(const float4v*)(p + 4);
            uint4v pk;
            pk[0] = pk2(lo[0], lo[1]); pk[1] = pk2(lo[2], lo[3]);
            pk[2] = pk2(hi[0], hi[1]); pk[3] = pk2(hi[2], hi[3]);
            union { uint4v u; short8 s; } cvt; cvt.u = pk;
            a[mt] = cvt.s;
        }
        short8 bf[2];
        #pragma unroll
        for (int nt = 0; nt < 2; ++nt)
            bf[nt] = *(const short8*)(bB + (size_t)nt * 16 * NH + ks * 32);
        #pragma unroll
        for (int mt = 0; mt < 4; ++mt)
            #pragma unroll
            for (int nt = 0; nt < 2; ++nt)
                acc[mt][nt] = __builtin_amdgcn_mfma_f32_16x16x32_bf16(a[mt], bf[nt], acc[mt][nt], 0, 0, 0);
    }

    // C/D layout: col=lane&15, row=(lane>>4)*4+r  [m89-verified, passed R1-R3]
    #pragma unroll
    for (int mt = 0; mt < 4; ++mt)
        #pragma unroll
        for (int nt = 0; nt < 2; ++nt)
            #pragma unroll
            for (int r = 0; r < 4; ++r) {
                size_t row = r0 + mt * 16 + kg * 4 + r;
                P[row * ND + c0 + nt * 16 + cl] = f2bf(acc[mt][nt][r]);
            }
}

// one wave per (b,w): mean of P token-rows (bf16, L2-hot) + bias -> out fp32
__global__ __launch_bounds__(256)
void pool(const unsigned short* __restrict__ P, const int* __restrict__ bounds,
          const float* __restrict__ bias, float* __restrict__ out) {
    const int wave = threadIdx.x >> 6, lane = threadIdx.x & 63;
    const int idx = blockIdx.x * 4 + wave;           // 0..16383
    const int b = idx >> 8, w = idx & 255;
    int s = __builtin_amdgcn_readfirstlane(bounds[b * (NW + 1) + w]);
    int e = __builtin_amdgcn_readfirstlane(bounds[b * (NW + 1) + w + 1]);

    const unsigned short* base = P + (size_t)b * NT * ND + lane * 4;
    float a0 = 0.f, a1 = 0.f, a2 = 0.f, a3 = 0.f;

    int t = s;
    for (; t + 4 <= e; t += 4) {                     // 4 rows in flight
        ushort4v v0 = *(const ushort4v*)(base + (size_t)(t    ) * ND);
        ushort4v v1 = *(const ushort4v*)(base + (size_t)(t + 1) * ND);
        ushort4v v2 = *(const ushort4v*)(base + (size_t)(t + 2) * ND);
        ushort4v v3 = *(const ushort4v*)(base + (size_t)(t + 3) * ND);
        union { unsigned u; float f; } c;
        #define ADD(v) { c.u = (unsigned)(v)[0] << 16; a0 += c.f; \
                         c.u = (unsigned)(v)[1] << 16; a1 += c.f; \
                         c.u = (unsigned)(v)[2] << 16; a2 += c.f; \
                         c.u = (unsigned)(v)[3] << 16; a3 += c.f; }
        ADD(v0) ADD(v1) ADD(v2) ADD(v3)
    }
    for (; t < e; ++t) {
        ushort4v v = *(const ushort4v*)(base + (size_t)t * ND);
        union { unsigned u; float f; } c;
        ADD(v)
        #undef ADD
    }

    int cnt = e - s; if (cnt < 1) cnt = 1;
    float sc = 1.0f / (float)cnt;
    float4v bv = *(const float4v*)(bias + lane * 4);
    float4v o;
    o[0] = a0 * sc + bv[0]; o[1] = a1 * sc + bv[1];
    o[2] = a2 * sc + bv[2]; o[3] = a3 * sc + bv[3];
    *(float4v*)(out + ((size_t)b * NW + w) * ND + lane * 4) = o;
}

extern "C" void kernel_launch(void* const* d_in, const int* in_sizes, int n_in,
                              void* d_out, int out_size, void* d_ws, size_t ws_size,
                              hipStream_t stream) {
    const float* hs  = (const float*)d_in[0];
    const int*   wid = (const int*)d_in[1];
    const float* pw  = (const float*)d_in[2];
    const float* pb  = (const float*)d_in[3];
    float* out = (float*)d_out;

    unsigned short* wt = (unsigned short*)d_ws;                      // 393216 B
    int* bounds        = (int*)((char*)d_ws + 393216);               // 65792 B
    unsigned short* P  = (unsigned short*)((char*)d_ws + 524288);    // 16777216 B

    dim3 gp(NH / 32, ND / 32);
    prep_wt<<<gp, 256, 0, stream>>>(pw, wt);
    prep_bounds<<<NB, 256, 0, stream>>>(wid, bounds);
    gemm_tok<<<(NB * NT) / 64, 512, 0, stream>>>(hs, wt, P);
    pool<<<(NB * NW) / 4, 256, 0, stream>>>(P, bounds, pb, out);
}

// Round 5
// 78.378 us; speedup vs baseline: 1.6555x; 1.6555x over previous
//
#include <hip/hip_runtime.h>

// BertWordEmbedder: B=64, T=512, H=768, W=256, D=256
// Pool-first (half the GEMM FLOPs), both stages occupancy-first:
//   prep_wt:     proj_w [768][256] f32 -> wt [256][768] bf16        (d_ws)
//   prep_bounds: bounds[b][w] = lower_bound(wid[b,:], w)            (d_ws)
//   pool_gather: one WAVE per (b,w): mean of hs token rows -> we bf16 [16384][768]
//   gemm2:       out = we @ W + bias.  BM=32 x BN=128 -> 1024 blocks,
//                direct-global fragments (we/wt are L2/L3-hot), unroll-4 pipeline.
// Empty words: we row = 0 -> out = bias (matches reference).
// ws: [0) wt 393216 | [393216) bounds 65792 | [524288) we 25165824

#define NB 64
#define NT 512
#define NH 768
#define NW 256
#define ND 256

typedef __attribute__((ext_vector_type(8))) short short8;
typedef __attribute__((ext_vector_type(4))) float f32x4;
typedef __attribute__((ext_vector_type(4))) float float4v;
typedef __attribute__((ext_vector_type(4))) unsigned short ushort4v;

__device__ __forceinline__ unsigned short f2bf(float f) {
    union { float f; unsigned u; } v; v.f = f;
    unsigned r = v.u + 0x7fffu + ((v.u >> 16) & 1u);  // RNE
    return (unsigned short)(r >> 16);
}

// proj_w [H][D] fp32 -> wt [D][H] bf16
__global__ void prep_wt(const float* __restrict__ w, unsigned short* __restrict__ wt) {
    __shared__ float tile[32][33];
    int tx = threadIdx.x & 31, ty = threadIdx.x >> 5;
    int k0 = blockIdx.x * 32, n0 = blockIdx.y * 32;
    #pragma unroll
    for (int i = 0; i < 4; ++i)
        tile[ty + 8 * i][tx] = w[(size_t)(k0 + ty + 8 * i) * ND + n0 + tx];
    __syncthreads();
    #pragma unroll
    for (int i = 0; i < 4; ++i)
        wt[(size_t)(n0 + ty + 8 * i) * NH + k0 + tx] = f2bf(tile[tx][ty + 8 * i]);
}

// bounds[b][w] = lower_bound(wid[b,:], w), w in [0, NW]; stride NW+1
__global__ void prep_bounds(const int* __restrict__ wid, int* __restrict__ bounds) {
    __shared__ int s[NT];
    int b = blockIdx.x, tid = threadIdx.x;
    s[tid]       = wid[b * NT + tid];
    s[tid + 256] = wid[b * NT + tid + 256];
    __syncthreads();
    for (int w = tid; w <= NW; w += 256) {
        int lo = 0, hi = NT;
        while (lo < hi) { int m = (lo + hi) >> 1; if (s[m] < w) lo = m + 1; else hi = m; }
        bounds[b * (NW + 1) + w] = lo;
    }
}

// one wave per (b,w): mean of hs token rows -> bf16 we row  (R3-proven)
__global__ __launch_bounds__(256) void pool_gather(const float* __restrict__ hs,
                                                   const int* __restrict__ bounds,
                                                   unsigned short* __restrict__ we) {
    const int wave = threadIdx.x >> 6, lane = threadIdx.x & 63;
    const int idx = blockIdx.x * 4 + wave;           // 0..16383
    const int b = idx >> 8, w = idx & 255;
    int s = __builtin_amdgcn_readfirstlane(bounds[b * (NW + 1) + w]);
    int e = __builtin_amdgcn_readfirstlane(bounds[b * (NW + 1) + w + 1]);

    const float* base = hs + (size_t)b * NT * NH + lane * 4;
    float4v a0 = {0,0,0,0}, a1 = {0,0,0,0}, a2 = {0,0,0,0};

    int t = s;
    for (; t + 2 <= e; t += 2) {                     // 6 loads in flight
        const float* p0 = base + (size_t)t * NH;
        const float* p1 = base + (size_t)(t + 1) * NH;
        float4v x0 = *(const float4v*)(p0);
        float4v x1 = *(const float4v*)(p0 + 256);
        float4v x2 = *(const float4v*)(p0 + 512);
        float4v y0 = *(const float4v*)(p1);
        float4v y1 = *(const float4v*)(p1 + 256);
        float4v y2 = *(const float4v*)(p1 + 512);
        #pragma unroll
        for (int j = 0; j < 4; ++j) {
            a0[j] += x0[j] + y0[j]; a1[j] += x1[j] + y1[j]; a2[j] += x2[j] + y2[j];
        }
    }
    if (t < e) {
        const float* p0 = base + (size_t)t * NH;
        float4v x0 = *(const float4v*)(p0);
        float4v x1 = *(const float4v*)(p0 + 256);
        float4v x2 = *(const float4v*)(p0 + 512);
        #pragma unroll
        for (int j = 0; j < 4; ++j) { a0[j] += x0[j]; a1[j] += x1[j]; a2[j] += x2[j]; }
    }

    int cnt = e - s; if (cnt < 1) cnt = 1;
    float sc = 1.0f / (float)cnt;
    unsigned short* dst = we + (size_t)idx * NH + lane * 4;
    ushort4v u0, u1, u2;
    #pragma unroll
    for (int j = 0; j < 4; ++j) {
        u0[j] = f2bf(a0[j] * sc); u1[j] = f2bf(a1[j] * sc); u2[j] = f2bf(a2[j] * sc);
    }
    *(ushort4v*)(dst)       = u0;
    *(ushort4v*)(dst + 256) = u1;
    *(ushort4v*)(dst + 512) = u2;
}

// out[16384x256] = we[16384x768] @ wt^T + bias.
// 1024 blocks (BM=32 x BN=128), 256 thr = 4 waves, wave = 32x32 tile.
// Fragments direct from global (we: L2/L3-hot, wt: L2-hot); 4 base pointers,
// k-step advances via immediate offsets; unroll 4 -> 16 loads in flight.
__global__ __launch_bounds__(256, 4)
void gemm2(const unsigned short* __restrict__ we, const unsigned short* __restrict__ wt,
           const float* __restrict__ bias, float* __restrict__ out) {
    const int tid = threadIdx.x, wave = tid >> 6, lane = tid & 63;
    const int cl = lane & 15, kg = lane >> 4;
    const size_t r0 = (size_t)blockIdx.x * 32;
    const int c0 = blockIdx.y * 128 + wave * 32;

    const unsigned short* a0p = we + (r0 + cl) * NH + kg * 8;
    const unsigned short* a1p = a0p + 16 * NH;
    const unsigned short* b0p = wt + (size_t)(c0 + cl) * NH + kg * 8;
    const unsigned short* b1p = b0p + 16 * NH;

    f32x4 acc[2][2];
    #pragma unroll
    for (int mt = 0; mt < 2; ++mt)
        #pragma unroll
        for (int nt = 0; nt < 2; ++nt)
            #pragma unroll
            for (int r = 0; r < 4; ++r) acc[mt][nt][r] = 0.f;

    #pragma unroll 4
    for (int ks = 0; ks < NH / 32; ++ks) {           // 24 K-steps, +64B per step
        short8 a0 = *(const short8*)(a0p + ks * 32);
        short8 a1 = *(const short8*)(a1p + ks * 32);
        short8 b0 = *(const short8*)(b0p + ks * 32);
        short8 b1 = *(const short8*)(b1p + ks * 32);
        acc[0][0] = __builtin_amdgcn_mfma_f32_16x16x32_bf16(a0, b0, acc[0][0], 0, 0, 0);
        acc[0][1] = __builtin_amdgcn_mfma_f32_16x16x32_bf16(a0, b1, acc[0][1], 0, 0, 0);
        acc[1][0] = __builtin_amdgcn_mfma_f32_16x16x32_bf16(a1, b0, acc[1][0], 0, 0, 0);
        acc[1][1] = __builtin_amdgcn_mfma_f32_16x16x32_bf16(a1, b1, acc[1][1], 0, 0, 0);
    }

    float bv[2];
    bv[0] = bias[c0 + cl];
    bv[1] = bias[c0 + 16 + cl];

    // C/D layout: col=lane&15, row=(lane>>4)*4+r  [proven R1-R4]
    #pragma unroll
    for (int mt = 0; mt < 2; ++mt)
        #pragma unroll
        for (int nt = 0; nt < 2; ++nt)
            #pragma unroll
            for (int r = 0; r < 4; ++r)
                out[(r0 + mt * 16 + kg * 4 + r) * ND + c0 + nt * 16 + cl] = acc[mt][nt][r] + bv[nt];
}

extern "C" void kernel_launch(void* const* d_in, const int* in_sizes, int n_in,
                              void* d_out, int out_size, void* d_ws, size_t ws_size,
                              hipStream_t stream) {
    const float* hs  = (const float*)d_in[0];
    const int*   wid = (const int*)d_in[1];
    const float* pw  = (const float*)d_in[2];
    const float* pb  = (const float*)d_in[3];
    float* out = (float*)d_out;

    unsigned short* wt = (unsigned short*)d_ws;                      // 393216 B
    int* bounds        = (int*)((char*)d_ws + 393216);               // 65792 B
    unsigned short* we = (unsigned short*)((char*)d_ws + 524288);    // 25165824 B

    dim3 gp(NH / 32, ND / 32);
    prep_wt<<<gp, 256, 0, stream>>>(pw, wt);
    prep_bounds<<<NB, 256, 0, stream>>>(wid, bounds);
    pool_gather<<<(NB * NW) / 4, 256, 0, stream>>>(hs, bounds, we);
    dim3 gg(NB * NW / 32, ND / 128);
    gemm2<<<gg, 256, 0, stream>>>(we, wt, pb, out);
}

// Round 6
// 48.801 us; speedup vs baseline: 2.6588x; 1.6061x over previous
//
#include <hip/hip_runtime.h>

// BertWordEmbedder: B=64, T=512, H=768, W=256, D=256
//   prep_wt:     proj_w [768][256] f32 -> wt [256][768] bf16        (d_ws)
//   prep_bounds: bounds[b][w] = lower_bound(wid[b,:], w)            (d_ws)
//   pool_gather: one WAVE per (b,w): mean of hs token rows -> we bf16 [16384][768]
//   gemm_lds:    out = we @ wt^T + bias, m97-style LDS-staged MFMA GEMM
//                BM=128 BN=64 BK=64, reg-staged w/ early-issue prefetch, padded LDS.
// Empty words: we row = 0 -> out = bias (matches reference).
// ws: [0) wt 393216 | [393216) bounds 65792 | [524288) we 25165824

#define NB 64
#define NT 512
#define NH 768
#define NW 256
#define ND 256

typedef __attribute__((ext_vector_type(8))) short short8;
typedef __attribute__((ext_vector_type(4))) float f32x4;
typedef __attribute__((ext_vector_type(4))) float float4v;
typedef __attribute__((ext_vector_type(4))) unsigned int uint4v;
typedef __attribute__((ext_vector_type(4))) unsigned short ushort4v;

__device__ __forceinline__ unsigned short f2bf(float f) {
    union { float f; unsigned u; } v; v.f = f;
    unsigned r = v.u + 0x7fffu + ((v.u >> 16) & 1u);  // RNE
    return (unsigned short)(r >> 16);
}

// proj_w [H][D] fp32 -> wt [D][H] bf16
__global__ void prep_wt(const float* __restrict__ w, unsigned short* __restrict__ wt) {
    __shared__ float tile[32][33];
    int tx = threadIdx.x & 31, ty = threadIdx.x >> 5;
    int k0 = blockIdx.x * 32, n0 = blockIdx.y * 32;
    #pragma unroll
    for (int i = 0; i < 4; ++i)
        tile[ty + 8 * i][tx] = w[(size_t)(k0 + ty + 8 * i) * ND + n0 + tx];
    __syncthreads();
    #pragma unroll
    for (int i = 0; i < 4; ++i)
        wt[(size_t)(n0 + ty + 8 * i) * NH + k0 + tx] = f2bf(tile[tx][ty + 8 * i]);
}

// bounds[b][w] = lower_bound(wid[b,:], w), w in [0, NW]; stride NW+1
__global__ void prep_bounds(const int* __restrict__ wid, int* __restrict__ bounds) {
    __shared__ int s[NT];
    int b = blockIdx.x, tid = threadIdx.x;
    s[tid]       = wid[b * NT + tid];
    s[tid + 256] = wid[b * NT + tid + 256];
    __syncthreads();
    for (int w = tid; w <= NW; w += 256) {
        int lo = 0, hi = NT;
        while (lo < hi) { int m = (lo + hi) >> 1; if (s[m] < w) lo = m + 1; else hi = m; }
        bounds[b * (NW + 1) + w] = lo;
    }
}

// one wave per (b,w): mean of hs token rows -> bf16 we row (CONTROL: unchanged)
__global__ __launch_bounds__(256) void pool_gather(const float* __restrict__ hs,
                                                   const int* __restrict__ bounds,
                                                   unsigned short* __restrict__ we) {
    const int wave = threadIdx.x >> 6, lane = threadIdx.x & 63;
    const int idx = blockIdx.x * 4 + wave;           // 0..16383
    const int b = idx >> 8, w = idx & 255;
    int s = __builtin_amdgcn_readfirstlane(bounds[b * (NW + 1) + w]);
    int e = __builtin_amdgcn_readfirstlane(bounds[b * (NW + 1) + w + 1]);

    const float* base = hs + (size_t)b * NT * NH + lane * 4;
    float4v a0 = {0,0,0,0}, a1 = {0,0,0,0}, a2 = {0,0,0,0};

    int t = s;
    for (; t + 2 <= e; t += 2) {                     // 6 loads in flight
        const float* p0 = base + (size_t)t * NH;
        const float* p1 = base + (size_t)(t + 1) * NH;
        float4v x0 = *(const float4v*)(p0);
        float4v x1 = *(const float4v*)(p0 + 256);
        float4v x2 = *(const float4v*)(p0 + 512);
        float4v y0 = *(const float4v*)(p1);
        float4v y1 = *(const float4v*)(p1 + 256);
        float4v y2 = *(const float4v*)(p1 + 512);
        #pragma unroll
        for (int j = 0; j < 4; ++j) {
            a0[j] += x0[j] + y0[j]; a1[j] += x1[j] + y1[j]; a2[j] += x2[j] + y2[j];
        }
    }
    if (t < e) {
        const float* p0 = base + (size_t)t * NH;
        float4v x0 = *(const float4v*)(p0);
        float4v x1 = *(const float4v*)(p0 + 256);
        float4v x2 = *(const float4v*)(p0 + 512);
        #pragma unroll
        for (int j = 0; j < 4; ++j) { a0[j] += x0[j]; a1[j] += x1[j]; a2[j] += x2[j]; }
    }

    int cnt = e - s; if (cnt < 1) cnt = 1;
    float sc = 1.0f / (float)cnt;
    unsigned short* dst = we + (size_t)idx * NH + lane * 4;
    ushort4v u0, u1, u2;
    #pragma unroll
    for (int j = 0; j < 4; ++j) {
        u0[j] = f2bf(a0[j] * sc); u1[j] = f2bf(a1[j] * sc); u2[j] = f2bf(a2[j] * sc);
    }
    *(ushort4v*)(dst)       = u0;
    *(ushort4v*)(dst + 256) = u1;
    *(ushort4v*)(dst + 512) = u2;
}

// out[16384x256] = we[16384x768] @ wt^T + bias.  m97-style LDS-staged GEMM.
// BM=128 BN=64 BK=64. 256 thr = 4 waves (2x2), wave = 64x32 (4x2 frags).
// Reg-staged: next K-tile's global loads ISSUE between the barriers (latency
// hides under MFMA); LDS rows padded +8 ushorts (144B stride, no conflicts).
__global__ __launch_bounds__(256)
void gemm_lds(const unsigned short* __restrict__ we, const unsigned short* __restrict__ wt,
              const float* __restrict__ bias, float* __restrict__ out) {
    __shared__ unsigned short Asm[128][72];   // [BM][BK+8]
    __shared__ unsigned short Bsm[64][72];    // [BN][BK+8]

    const int tid = threadIdx.x, wave = tid >> 6, lane = tid & 63;
    const int cl = lane & 15, kg = lane >> 4;
    const size_t r0 = (size_t)blockIdx.x * 128;
    const int c0 = blockIdx.y * 64;
    const int wm0 = (wave >> 1) * 64, wn0 = (wave & 1) * 32;

    // staging assignment: A: 2 thr/row x 4 chunks; B: 4 thr/row x 2 chunks
    const int arow = tid >> 1, ah = tid & 1;
    const int brow = tid >> 2, bq = tid & 3;
    const unsigned short* agp = we + (r0 + arow) * NH;
    const unsigned short* bgp = wt + (size_t)(c0 + brow) * NH;

    uint4v sA0[4], sB0[2], sA1[4], sB1[2];

    auto gload = [&](uint4v* sA, uint4v* sB, int k0e) {
        #pragma unroll
        for (int i = 0; i < 4; ++i)
            sA[i] = *(const uint4v*)(agp + k0e + (ah + 2 * i) * 8);
        #pragma unroll
        for (int i = 0; i < 2; ++i)
            sB[i] = *(const uint4v*)(bgp + k0e + (bq + 4 * i) * 8);
    };
    auto swrite = [&](uint4v* sA, uint4v* sB) {
        #pragma unroll
        for (int i = 0; i < 4; ++i)
            *(uint4v*)&Asm[arow][(ah + 2 * i) * 8] = sA[i];
        #pragma unroll
        for (int i = 0; i < 2; ++i)
            *(uint4v*)&Bsm[brow][(bq + 4 * i) * 8] = sB[i];
    };

    f32x4 acc[4][2];
    #pragma unroll
    for (int mt = 0; mt < 4; ++mt)
        #pragma unroll
        for (int nt = 0; nt < 2; ++nt)
            #pragma unroll
            for (int r = 0; r < 4; ++r) acc[mt][nt][r] = 0.f;

    auto compute = [&]() {
        short8 af[4][2], bf[2][2];
        #pragma unroll
        for (int mt = 0; mt < 4; ++mt)
            #pragma unroll
            for (int km = 0; km < 2; ++km)
                af[mt][km] = *(const short8*)&Asm[wm0 + mt * 16 + cl][km * 32 + kg * 8];
        #pragma unroll
        for (int nt = 0; nt < 2; ++nt)
            #pragma unroll
            for (int km = 0; km < 2; ++km)
                bf[nt][km] = *(const short8*)&Bsm[wn0 + nt * 16 + cl][km * 32 + kg * 8];
        #pragma unroll
        for (int mt = 0; mt < 4; ++mt)
            #pragma unroll
            for (int nt = 0; nt < 2; ++nt)
                #pragma unroll
                for (int km = 0; km < 2; ++km)
                    acc[mt][nt] = __builtin_amdgcn_mfma_f32_16x16x32_bf16(af[mt][km], bf[nt][km], acc[mt][nt], 0, 0, 0);
    };

    gload(sA0, sB0, 0);
    for (int ks = 0; ks < 12; ks += 2) {             // 12 K-steps of 64
        swrite(sA0, sB0);
        __syncthreads();
        gload(sA1, sB1, (ks + 1) * 64);              // issue early, lands later
        compute();
        __syncthreads();
        swrite(sA1, sB1);
        __syncthreads();
        if (ks + 2 < 12) gload(sA0, sB0, (ks + 2) * 64);
        compute();
        __syncthreads();
    }

    float bv[2];
    bv[0] = bias[c0 + wn0 + cl];
    bv[1] = bias[c0 + wn0 + 16 + cl];

    // C/D layout: col=lane&15, row=(lane>>4)*4+r  [proven R1-R5]
    #pragma unroll
    for (int mt = 0; mt < 4; ++mt)
        #pragma unroll
        for (int nt = 0; nt < 2; ++nt)
            #pragma unroll
            for (int r = 0; r < 4; ++r)
                out[(r0 + wm0 + mt * 16 + kg * 4 + r) * ND + c0 + wn0 + nt * 16 + cl]
                    = acc[mt][nt][r] + bv[nt];
}

extern "C" void kernel_launch(void* const* d_in, const int* in_sizes, int n_in,
                              void* d_out, int out_size, void* d_ws, size_t ws_size,
                              hipStream_t stream) {
    const float* hs  = (const float*)d_in[0];
    const int*   wid = (const int*)d_in[1];
    const float* pw  = (const float*)d_in[2];
    const float* pb  = (const float*)d_in[3];
    float* out = (float*)d_out;

    unsigned short* wt = (unsigned short*)d_ws;                      // 393216 B
    int* bounds        = (int*)((char*)d_ws + 393216);               // 65792 B
    unsigned short* we = (unsigned short*)((char*)d_ws + 524288);    // 25165824 B

    dim3 gp(NH / 32, ND / 32);
    prep_wt<<<gp, 256, 0, stream>>>(pw, wt);
    prep_bounds<<<NB, 256, 0, stream>>>(wid, bounds);
    pool_gather<<<(NB * NW) / 4, 256, 0, stream>>>(hs, bounds, we);
    dim3 gg(NB * NW / 128, ND / 64);
    gemm_lds<<<gg, 256, 0, stream>>>(we, wt, pb, out);
}